// Round 1
// 446.343 us; speedup vs baseline: 1.0711x; 1.0711x over previous
//
#include <hip/hip_runtime.h>
#include <hip/hip_bf16.h>

#define B_ 8
#define C_ 1536
#define T_ 4096
#define A_ 128
#define K3_ 4608        // 3*C columns of W1
#define M32_ 128        // T / 32 chunks
#define KP_ 200         // k2 tile row stride (f16 elems)

typedef _Float16 h8  __attribute__((ext_vector_type(8)));
typedef _Float16 h2v __attribute__((ext_vector_type(2)));
typedef float    f4  __attribute__((ext_vector_type(4)));

// ---------------- kernel 0: W1 fp32 -> f16, MFMA A-fragment order -----------
// W1f[((kb*8 + t8)*64 + lane)*8 + j] = W1[a=t8*16+(lane&15)][k=kb*32+(lane>>4)*8+j]
__global__ void k0_pack(const float* __restrict__ W1, _Float16* __restrict__ W1f) {
    int i = blockIdx.x * 256 + threadIdx.x;
    if (i >= A_ * K3_) return;
    int a = i / K3_, k = i - a * K3_;
    int t8 = a >> 4, r15 = a & 15;
    int kb = k >> 5, q = (k >> 3) & 3, j = k & 7;
    int lane = q * 16 + r15;
    W1f[(size_t)((kb * 8 + t8) * 64 + lane) * 8 + j] = (_Float16)W1[i];
}

// ---------------- kernel 1: per-(b,c) 32-t-chunk carries --------------------
// COALESCED version: lane L owns float4 (g*64 + L)  -> each load instruction
// covers 1 KB contiguous. Chunk (32 t) = 8 consecutive lanes within one g.
// Hierarchy: intra-float4 masked sums -> 8-lane xor-reduce (= chunk totals)
// -> stride-8 scan over the 8 chunks of this g -> serial row base across g.
__global__ __launch_bounds__(256) void k1_carry(
    const float* __restrict__ x, const int* __restrict__ lens,
    float2* __restrict__ carry)
{
    const int rowid = blockIdx.x * 4 + (threadIdx.x >> 6);
    const int lane  = threadIdx.x & 63;
    const int b     = rowid / C_;
    const int len   = lens[b];                 // uniform per wave
    const float* xr = x + (size_t)rowid * T_;
    float2* cp = carry + (size_t)rowid * M32_;

    const int grp = lane >> 3;                 // chunk index within g (0..7)
    float base1 = 0.f, base2 = 0.f;

#pragma unroll
    for (int g = 0; g < 16; ++g) {
        const int t0g = g * 256;
        if (t0g >= len) {                      // wave-uniform: all-masked tail
            if ((lane & 7) == 0) cp[g * 8 + grp] = make_float2(base1, base2);
            continue;
        }
        float4 v = *(const float4*)(xr + t0g + lane * 4);
        float s1, s2;
        if (t0g + 256 <= len) {                // wave-uniform: fully in-range
            s1 = v.x + v.y + v.z + v.w;
            s2 = v.x * v.x + v.y * v.y + v.z * v.z + v.w * v.w;
        } else {                               // boundary g: per-element mask
            const int tb = t0g + lane * 4;
            float vs[4] = {v.x, v.y, v.z, v.w};
            s1 = 0.f; s2 = 0.f;
#pragma unroll
            for (int j = 0; j < 4; ++j) {
                float m = (tb + j < len) ? vs[j] : 0.f;
                s1 += m; s2 += m * vs[j];
            }
        }
        // 8-lane group totals (every lane of the group gets the chunk total)
        float g1 = s1, g2 = s2;
        g1 += __shfl_xor(g1, 1, 64); g2 += __shfl_xor(g2, 1, 64);
        g1 += __shfl_xor(g1, 2, 64); g2 += __shfl_xor(g2, 2, 64);
        g1 += __shfl_xor(g1, 4, 64); g2 += __shfl_xor(g2, 4, 64);
        // inclusive scan over the 8 chunk totals (stride-8 Hillis-Steele)
        float V1 = g1, V2 = g2;
#pragma unroll
        for (int d = 8; d < 64; d <<= 1) {
            float o1 = __shfl_up(V1, d, 64);
            float o2 = __shfl_up(V2, d, 64);
            if (lane >= d) { V1 += o1; V2 += o2; }
        }
        const float e1 = V1 - g1, e2 = V2 - g2;   // exclusive: chunks < grp
        if ((lane & 7) == 0) {
            cp[g * 8 + grp] = make_float2(base1 + e1, base2 + e2);
        }
        base1 += __shfl(V1, 63, 64);              // row total of this g
        base2 += __shfl(V2, 63, 64);
    }
}

// ---------------- kernel 2: fused causal-stats + full-K GEMM(tanh) + W2 -----
// grid 1024 = (b, 32-t chunk). c-step 64. A-frags from pre-packed W1f
// (coalesced 1KB/wave loads). B-tile in LDS, stride 200, XOR-swizzled.
__global__ __launch_bounds__(256) void k2_gemm(
    const float* __restrict__ x, const int* __restrict__ lens,
    const float2* __restrict__ carry, const _Float16* __restrict__ W1f,
    const float* __restrict__ b1, const float* __restrict__ W2,
    float* __restrict__ logits)
{
    __shared__ _Float16 tile[32][KP_];   // 12.5 KB
    __shared__ float s_w2[A_], s_b1[A_];
    __shared__ float lpart[2][32];

    const int tid = threadIdx.x;
    // swizzled block id: i = (m&7)*128 + b*16 + (m>>3)
    const int i    = blockIdx.x;
    const int mlow = i >> 7;
    const int b    = (i >> 4) & 7;
    const int m    = ((i & 15) << 3) | mlow;
    const int t0   = m << 5;
    const int len  = lens[b];

    if (tid < A_) { s_w2[tid] = W2[tid]; s_b1[tid] = b1[tid]; }

    // phase-A mapping: 32 channel-pairs x 8 t-segments (4 t each)
    const int cp  = tid >> 3;      // 0..31
    const int sgm = tid & 7;       // 0..7
    const int tb  = t0 + sgm * 4;

    // phase-C mapping
    const int lane = tid & 63;
    const int w    = tid >> 6;
    const int mtg  = w & 1;        // m-half (64 a-rows)
    const int ntg  = w >> 1;       // n-tile (16 t)
    const int ln15 = lane & 15, q = lane >> 4;
    const h8* W1f8 = (const h8*)W1f;

    f4 acc[4] = {};

    for (int c0 = 0; c0 < C_; c0 += 64) {
        // ---- phase A: stats for 64 channels x 32 t ----
        const size_t rowA = (size_t)b * C_ + c0 + cp * 2;
        const float* xpA = x + rowA * T_ + tb;
        float4 va = *(const float4*)xpA;
        float4 vb = *(const float4*)(xpA + T_);
        float xa[4] = {va.x, va.y, va.z, va.w};
        float xb[4] = {vb.x, vb.y, vb.z, vb.w};
        float pA1[4], pA2[4], pB1[4], pB2[4];
        float a1 = 0.f, a2 = 0.f, c1 = 0.f, c2 = 0.f;
#pragma unroll
        for (int j = 0; j < 4; ++j) {
            bool in = (tb + j) < len;
            float ma = in ? xa[j] : 0.f;
            float mb = in ? xb[j] : 0.f;
            a1 += ma; a2 += ma * xa[j]; pA1[j] = a1; pA2[j] = a2;
            c1 += mb; c2 += mb * xb[j]; pB1[j] = c1; pB2[j] = c2;
        }
        float t1 = a1, t2 = a2, t3 = c1, t4 = c2;
#pragma unroll
        for (int d = 1; d < 8; d <<= 1) {
            float o1 = __shfl_up(t1, d, 8);
            float o2 = __shfl_up(t2, d, 8);
            float o3 = __shfl_up(t3, d, 8);
            float o4 = __shfl_up(t4, d, 8);
            if (sgm >= d) { t1 += o1; t2 += o2; t3 += o3; t4 += o4; }
        }
        const float eA1 = t1 - a1, eA2 = t2 - a2;
        const float eB1 = t3 - c1, eB2 = t4 - c2;
        const float2 crA = carry[rowA * M32_ + m];
        const float2 crB = carry[(rowA + 1) * M32_ + m];
        const int cb = cp >> 2;               // 8-elem k-block 0..7
        const int co = (cp & 3) * 2;
#pragma unroll
        for (int j = 0; j < 4; ++j) {
            const int t  = tb + j;
            const int tl = sgm * 4 + j;       // 0..31
            float fn = (float)min(t + 1, len);
            float rn = __builtin_amdgcn_rcpf(fn);
            float S1a = crA.x + eA1 + pA1[j];
            float S2a = crA.y + eA2 + pA2[j];
            float mA = S1a * rn;
            float vA = S2a * rn - mA * mA;
            float dA = sqrtf(fmaxf(vA, 1e-12f));
            float S1b = crB.x + eB1 + pB1[j];
            float S2b = crB.y + eB2 + pB2[j];
            float mB = S1b * rn;
            float vB = S2b * rn - mB * mB;
            float dB = sqrtf(fmaxf(vB, 1e-12f));
            const int s  = (tl >> 3) & 3;
            const int xo = ((cb ^ s) << 3) + co;
            h2v px = {(_Float16)xa[j], (_Float16)xb[j]};
            h2v pm = {(_Float16)mA, (_Float16)mB};
            h2v pd = {(_Float16)dA, (_Float16)dB};
            *(h2v*)&tile[tl][xo]       = px;
            *(h2v*)&tile[tl][64 + xo]  = pm;
            *(h2v*)&tile[tl][128 + xo] = pd;
        }
        __syncthreads();
        // ---- phase C: 24 MFMAs/wave; af coalesced from W1f ----
        const int tl = ntg * 16 + ln15;
        const int s  = (tl >> 3) & 3;
        const int kb0 = c0 >> 5;
#pragma unroll
        for (int p = 0; p < 3; ++p) {
#pragma unroll
            for (int kk = 0; kk < 2; ++kk) {
                const int bb = (kk * 4 + q) ^ s;     // s<4: affects low 2 bits
                h8 bf = *(const h8*)&tile[tl][p * 64 + bb * 8];
                const int kbp = p * 48 + kb0 + kk;
#pragma unroll
                for (int ii = 0; ii < 4; ++ii) {
                    h8 af = W1f8[(kbp * 8 + mtg * 4 + ii) * 64 + lane];
                    acc[ii] = __builtin_amdgcn_mfma_f32_16x16x32_f16(af, bf, acc[ii], 0, 0, 0);
                }
            }
        }
        __syncthreads();
    }
    // ---- epilogue: tanh on full pre-activation + W2 reduction ----
    float pr = 0.f;
#pragma unroll
    for (int ii = 0; ii < 4; ++ii) {
#pragma unroll
        for (int rg = 0; rg < 4; ++rg) {
            int a = (mtg * 4 + ii) * 16 + q * 4 + rg;
            float h = acc[ii][rg] + s_b1[a];
            pr += tanhf(h) * s_w2[a];
        }
    }
    pr += __shfl_xor(pr, 16, 64);
    pr += __shfl_xor(pr, 32, 64);
    if (q == 0) lpart[mtg][ntg * 16 + ln15] = pr;
    __syncthreads();
    if (tid < 32) {
        logits[(size_t)b * T_ + t0 + tid] = lpart[0][tid] + lpart[1][tid];
    }
}

// ---------------- kernel 3: softmax prep (max, e, cumsum Z) per b -----------
__global__ __launch_bounds__(64) void k3_softmax(
    const float* __restrict__ logits, float* __restrict__ earr,
    float* __restrict__ zarr)
{
    const int b = blockIdx.x;
    const int l = threadIdx.x;
    const float* base = logits + (size_t)b * T_ + l * 64;
    float lg[64];
#pragma unroll
    for (int ii = 0; ii < 16; ++ii) {
        float4 v = *(const float4*)(base + ii * 4);
        lg[ii * 4 + 0] = v.x; lg[ii * 4 + 1] = v.y;
        lg[ii * 4 + 2] = v.z; lg[ii * 4 + 3] = v.w;
    }
    float mx = -3.4e38f;
#pragma unroll
    for (int i = 0; i < 64; ++i) mx = fmaxf(mx, lg[i]);
#pragma unroll
    for (int d = 1; d < 64; d <<= 1) mx = fmaxf(mx, __shfl_xor(mx, d, 64));
    float tot = 0.f;
#pragma unroll
    for (int i = 0; i < 64; ++i) { lg[i] = expf(lg[i] - mx); tot += lg[i]; }
    float V = tot;
#pragma unroll
    for (int d = 1; d < 64; d <<= 1) {
        float o = __shfl_up(V, d, 64);
        if (l >= d) V += o;
    }
    float run = V - tot;
    float* eo = earr + (size_t)b * T_ + l * 64;
    float* zo = zarr + (size_t)b * T_ + l * 64;
#pragma unroll
    for (int ii = 0; ii < 16; ++ii) {
        float4 ev, zv;
        float e0 = lg[ii * 4 + 0]; run += e0; ev.x = e0; zv.x = run;
        float e1 = lg[ii * 4 + 1]; run += e1; ev.y = e1; zv.y = run;
        float e2 = lg[ii * 4 + 2]; run += e2; ev.z = e2; zv.z = run;
        float e3 = lg[ii * 4 + 3]; run += e3; ev.w = e3; zv.w = run;
        *(float4*)(eo + ii * 4) = ev;
        *(float4*)(zo + ii * 4) = zv;
    }
}

// ---------------- kernel 4: weighted running mean/std + final reduce --------
// COALESCED single-pass version: lane L owns float4 (g*64 + L). Both outputs
// are sums of transforms of two inclusive prefixes:
//   S(t) = cumsum(e*x)                -> wm(t)  = S/Z,     am  += wm
//   D(t) = cumsum(e*(x - wm(t))^2)    -> var(t) = D/Z,     asd += sqrt(var)
// D's term at t only needs S(t), so one pass with two scans per g suffices.
__global__ __launch_bounds__(256) void k4_wstats(
    const float* __restrict__ x, const float* __restrict__ earr,
    const float* __restrict__ zarr, float* __restrict__ out)
{
    const int rowid = blockIdx.x * 4 + (threadIdx.x >> 6);
    const int lane  = threadIdx.x & 63;
    const int b = rowid / C_;
    const int c = rowid - b * C_;
    const float* xr = x + (size_t)rowid * T_;
    const float* er = earr + (size_t)b * T_;
    const float* zr = zarr + (size_t)b * T_;

    float am = 0.f, asd = 0.f;
    float baseS = 0.f, baseD = 0.f;

#pragma unroll
    for (int g = 0; g < 16; ++g) {
        const int off = g * 256 + lane * 4;
        float4 xv = *(const float4*)(xr + off);
        float4 ev = *(const float4*)(er + off);
        float4 zv = *(const float4*)(zr + off);
        // ---- S prefix: p_j inclusive within the float4 ----
        float s0 = ev.x * xv.x;
        float s1 = s0 + ev.y * xv.y;
        float s2 = s1 + ev.z * xv.z;
        float s3 = s2 + ev.w * xv.w;
        float V = s3;
#pragma unroll
        for (int d = 1; d < 64; d <<= 1) {
            float o = __shfl_up(V, d, 64);
            if (lane >= d) V += o;
        }
        const float Sx = baseS + (V - s3);     // exclusive base for this lane
        baseS += __shfl(V, 63, 64);
        const float rz0 = __builtin_amdgcn_rcpf(zv.x);
        const float rz1 = __builtin_amdgcn_rcpf(zv.y);
        const float rz2 = __builtin_amdgcn_rcpf(zv.z);
        const float rz3 = __builtin_amdgcn_rcpf(zv.w);
        const float wm0 = (Sx + s0) * rz0;
        const float wm1 = (Sx + s1) * rz1;
        const float wm2 = (Sx + s2) * rz2;
        const float wm3 = (Sx + s3) * rz3;
        am += (wm0 + wm1) + (wm2 + wm3);
        const float d0 = xv.x - wm0;
        const float d1 = xv.y - wm1;
        const float d2 = xv.z - wm2;
        const float d3 = xv.w - wm3;
        // ---- D prefix: q_j inclusive within the float4 ----
        float q0 = ev.x * d0 * d0;
        float q1 = q0 + ev.y * d1 * d1;
        float q2 = q1 + ev.z * d2 * d2;
        float q3 = q2 + ev.w * d3 * d3;
        float W = q3;
#pragma unroll
        for (int d = 1; d < 64; d <<= 1) {
            float o = __shfl_up(W, d, 64);
            if (lane >= d) W += o;
        }
        const float Dx = baseD + (W - q3);
        baseD += __shfl(W, 63, 64);
        const float v0 = (Dx + q0) * rz0;
        const float v1 = (Dx + q1) * rz1;
        const float v2 = (Dx + q2) * rz2;
        const float v3 = (Dx + q3) * rz3;
        asd += (sqrtf(fmaxf(v0, 1e-12f)) + sqrtf(fmaxf(v1, 1e-12f)))
             + (sqrtf(fmaxf(v2, 1e-12f)) + sqrtf(fmaxf(v3, 1e-12f)));
    }
#pragma unroll
    for (int d = 1; d < 64; d <<= 1) {
        am  += __shfl_xor(am, d, 64);
        asd += __shfl_xor(asd, d, 64);
    }
    if (lane == 0) {
        out[(size_t)b * (2 * C_) + c]      = am  * (1.f / 4096.f);
        out[(size_t)b * (2 * C_) + C_ + c] = asd * (1.f / 4096.f);
    }
}

extern "C" void kernel_launch(void* const* d_in, const int* in_sizes, int n_in,
                              void* d_out, int out_size, void* d_ws, size_t ws_size,
                              hipStream_t stream) {
    const float* x    = (const float*)d_in[0];
    const int*   lens = (const int*)d_in[1];
    const float* W1   = (const float*)d_in[2];
    const float* b1   = (const float*)d_in[3];
    const float* W2   = (const float*)d_in[4];
    float* out = (float*)d_out;

    char* ws = (char*)d_ws;
    // ws layout (14.16 MB):
    float2*    carry  = (float2*)ws;                     // 8*1536*128*8 = 12,582,912
    _Float16*  W1f    = (_Float16*)(ws + 12582912);      // 128*4608*2   =  1,179,648
    float*     logits = (float*)(ws + 13762560);         //                  131,072
    float*     earr   = (float*)(ws + 13893632);         //                  131,072
    float*     zarr   = (float*)(ws + 14024704);         //                  131,072

    k0_pack   <<<(A_ * K3_ + 255) / 256, 256, 0, stream>>>(W1, W1f);
    k1_carry  <<<(B_ * C_) / 4, 256, 0, stream>>>(x, lens, carry);
    k2_gemm   <<<B_ * M32_, 256, 0, stream>>>(x, lens, carry, W1f, b1, W2, logits);
    k3_softmax<<<B_, 64, 0, stream>>>(logits, earr, zarr);
    k4_wstats <<<(B_ * C_) / 4, 256, 0, stream>>>(x, earr, zarr, out);
}